// Round 1
// baseline (4596.245 us; speedup 1.0000x reference)
//
#include <hip/hip_runtime.h>
#include <math.h>

#define N_NODES 100000
#define N_EDGES 150000
#define D 512
#define H 8
#define DH 64
#define NEG_SLOPE 0.2f

// ---------- helpers ----------
__device__ __forceinline__ float bflo(unsigned int u) { return __uint_as_float(u << 16); }
__device__ __forceinline__ float bfhi(unsigned int u) { return __uint_as_float(u & 0xFFFF0000u); }
__device__ __forceinline__ float bf2f(unsigned short u) { return __uint_as_float(((unsigned int)u) << 16); }
__device__ __forceinline__ unsigned short f2bf(float f) {
    unsigned int u = __float_as_uint(f);
    unsigned int r = u + 0x7FFFu + ((u >> 16) & 1u);   // round-to-nearest-even
    return (unsigned short)(r >> 16);
}
// order-preserving float->u32 map for atomicMax-based segment max
__device__ __forceinline__ unsigned int fmap(float f) {
    unsigned int u = __float_as_uint(f);
    return (u & 0x80000000u) ? ~u : (u | 0x80000000u);
}
__device__ __forceinline__ float funmap(unsigned int m) {
    return __uint_as_float((m & 0x80000000u) ? (m & 0x7FFFFFFFu) : ~m);
}

// ---------- zero fill ----------
__global__ __launch_bounds__(256) void zero_kernel(float4* __restrict__ p, int n4) {
    int t = blockIdx.x * 256 + threadIdx.x;
    if (t < n4) p[t] = make_float4(0.f, 0.f, 0.f, 0.f);
}

// ---------- GEMM: C(bf16)[M,512] = A[M,512] @ W[512,512] + bias ----------
__global__ __launch_bounds__(256)
void gemm_bias_bf16(const float* __restrict__ A, const float* __restrict__ W,
                    const float* __restrict__ bias, unsigned short* __restrict__ C, int M)
{
    __shared__ float As[32][68];   // [k][row], row-stride 68 floats (16B-aligned rows)
    __shared__ float Bs[32][64];   // [k][col]
    const int tid = threadIdx.x;
    const int cb = blockIdx.x * 64;   // col tile (8 tiles)
    const int rb = blockIdx.y * 64;   // row tile
    const int tx = tid & 15, ty = tid >> 4;
    float acc[4][4] = {};
    for (int k0 = 0; k0 < D; k0 += 32) {
        #pragma unroll
        for (int j = 0; j < 8; ++j) {
            int idx = tid + j * 256;            // 0..2047
            int rr = idx >> 5, kk = idx & 31;
            int row = rb + rr;
            As[kk][rr] = (row < M) ? A[(size_t)row * D + k0 + kk] : 0.f;
        }
        #pragma unroll
        for (int j = 0; j < 8; ++j) {
            int idx = tid + j * 256;
            int kk = idx >> 6, cc = idx & 63;
            Bs[kk][cc] = W[(size_t)(k0 + kk) * D + cb + cc];
        }
        __syncthreads();
        #pragma unroll
        for (int kk = 0; kk < 32; ++kk) {
            float a[4], b[4];
            #pragma unroll
            for (int i = 0; i < 4; ++i) a[i] = As[kk][ty * 4 + i];
            #pragma unroll
            for (int j = 0; j < 4; ++j) b[j] = Bs[kk][tx * 4 + j];
            #pragma unroll
            for (int i = 0; i < 4; ++i)
                #pragma unroll
                for (int j = 0; j < 4; ++j)
                    acc[i][j] = fmaf(a[i], b[j], acc[i][j]);
        }
        __syncthreads();
    }
    #pragma unroll
    for (int i = 0; i < 4; ++i) {
        int row = rb + ty * 4 + i;
        if (row >= M) continue;
        #pragma unroll
        for (int j = 0; j < 4; ++j) {
            int col = cb + tx * 4 + j;
            C[(size_t)row * D + col] = f2bf(acc[i][j] + bias[col]);
        }
    }
}

// ---------- fused GEMM + tanh + column-sum (semantic attention K path) ----------
// ksum[f] += sum_rows tanh( (A @ W + bias)[row,f] )
__global__ __launch_bounds__(256)
void gemm_tanh_colsum(const float* __restrict__ A, const float* __restrict__ W,
                      const float* __restrict__ bias, float* __restrict__ ksum, int M)
{
    __shared__ float As[32][68];
    __shared__ float Bs[32][64];
    __shared__ float red[16][64];
    const int tid = threadIdx.x;
    const int cb = blockIdx.x * 64;
    const int rb = blockIdx.y * 64;
    const int tx = tid & 15, ty = tid >> 4;
    float acc[4][4] = {};
    for (int k0 = 0; k0 < D; k0 += 32) {
        #pragma unroll
        for (int j = 0; j < 8; ++j) {
            int idx = tid + j * 256;
            int rr = idx >> 5, kk = idx & 31;
            int row = rb + rr;
            As[kk][rr] = (row < M) ? A[(size_t)row * D + k0 + kk] : 0.f;
        }
        #pragma unroll
        for (int j = 0; j < 8; ++j) {
            int idx = tid + j * 256;
            int kk = idx >> 6, cc = idx & 63;
            Bs[kk][cc] = W[(size_t)(k0 + kk) * D + cb + cc];
        }
        __syncthreads();
        #pragma unroll
        for (int kk = 0; kk < 32; ++kk) {
            float a[4], b[4];
            #pragma unroll
            for (int i = 0; i < 4; ++i) a[i] = As[kk][ty * 4 + i];
            #pragma unroll
            for (int j = 0; j < 4; ++j) b[j] = Bs[kk][tx * 4 + j];
            #pragma unroll
            for (int i = 0; i < 4; ++i)
                #pragma unroll
                for (int j = 0; j < 4; ++j)
                    acc[i][j] = fmaf(a[i], b[j], acc[i][j]);
        }
        __syncthreads();
    }
    float s[4] = {0.f, 0.f, 0.f, 0.f};
    #pragma unroll
    for (int i = 0; i < 4; ++i) {
        int row = rb + ty * 4 + i;
        if (row < M) {
            #pragma unroll
            for (int j = 0; j < 4; ++j)
                s[j] += tanhf(acc[i][j] + bias[cb + tx * 4 + j]);
        }
    }
    #pragma unroll
    for (int j = 0; j < 4; ++j) red[ty][tx * 4 + j] = s[j];
    __syncthreads();
    if (tid < 64) {
        float tot = 0.f;
        #pragma unroll
        for (int g = 0; g < 16; ++g) tot += red[g][tid];
        atomicAdd(&ksum[cb + tid], tot);
    }
}

// ---------- a[n,h] = sum_d h[n,h,d] * att[h,d]  (h in bf16) ----------
__global__ __launch_bounds__(256)
void compute_a(const unsigned short* __restrict__ h, const float* __restrict__ att,
               float* __restrict__ a)
{
    int t = blockIdx.x * 256 + threadIdx.x;
    if (t >= N_NODES * H) return;
    int n = t >> 3, hh = t & 7;
    const uint4* hp = (const uint4*)(h + (size_t)n * D + hh * DH); // 16B = 8 bf16
    const float4* ap = (const float4*)(att + hh * DH);
    float s = 0.f;
    #pragma unroll
    for (int q = 0; q < 8; ++q) {
        uint4 u = hp[q];
        float4 w0 = ap[q * 2], w1 = ap[q * 2 + 1];
        s += bflo(u.x) * w0.x + bfhi(u.x) * w0.y
           + bflo(u.y) * w0.z + bfhi(u.y) * w0.w
           + bflo(u.z) * w1.x + bfhi(u.z) * w1.y
           + bflo(u.w) * w1.z + bfhi(u.w) * w1.w;
    }
    a[t] = s;
}

// ---------- init amax (-inf, mapped) and denom (0) ----------
__global__ __launch_bounds__(256)
void init_amax_denom(unsigned int* __restrict__ amax, float* __restrict__ denom)
{
    int t = blockIdx.x * 256 + threadIdx.x;
    if (t < N_NODES * H) { amax[t] = 0x007FFFFFu; denom[t] = 0.f; } // fmap(-inf)
}

// ---------- per-edge alpha -> segment max ----------
__global__ __launch_bounds__(256)
void edge_alpha_max(const int* __restrict__ src, const int* __restrict__ dst,
                    const float* __restrict__ a_src, const float* __restrict__ a_dst,
                    unsigned int* __restrict__ amax)
{
    int t = blockIdx.x * 256 + threadIdx.x;
    if (t >= N_EDGES * H) return;
    int e = t >> 3, hh = t & 7;
    int s = src[e], d = dst[e];
    float al = a_src[s * H + hh] + a_dst[d * H + hh];
    al = (al >= 0.f) ? al : NEG_SLOPE * al;
    atomicMax(&amax[d * H + hh], fmap(al));
}

// ---------- per-edge exp -> segment sum ----------
__global__ __launch_bounds__(256)
void edge_denom(const int* __restrict__ src, const int* __restrict__ dst,
                const float* __restrict__ a_src, const float* __restrict__ a_dst,
                const unsigned int* __restrict__ amax, float* __restrict__ denom)
{
    int t = blockIdx.x * 256 + threadIdx.x;
    if (t >= N_EDGES * H) return;
    int e = t >> 3, hh = t & 7;
    int s = src[e], d = dst[e];
    float al = a_src[s * H + hh] + a_dst[d * H + hh];
    al = (al >= 0.f) ? al : NEG_SLOPE * al;
    atomicAdd(&denom[d * H + hh], expf(al - funmap(amax[d * H + hh])));
}

// ---------- message scatter: one wave per edge ----------
__global__ __launch_bounds__(256)
void edge_scatter(const int* __restrict__ src, const int* __restrict__ dst,
                  const float* __restrict__ a_src, const float* __restrict__ a_dst,
                  const unsigned int* __restrict__ amax, const float* __restrict__ denom,
                  const unsigned short* __restrict__ h_src, float* __restrict__ out)
{
    int e = (blockIdx.x * 256 + threadIdx.x) >> 6;
    int lane = threadIdx.x & 63;
    if (e >= N_EDGES) return;
    int s = src[e], d = dst[e];
    const unsigned short* hp = h_src + (size_t)s * D;
    float* op = out + (size_t)d * D;
    #pragma unroll
    for (int i = 0; i < H; ++i) {
        float al = a_src[s * H + i] + a_dst[d * H + i];
        al = (al >= 0.f) ? al : NEG_SLOPE * al;
        float w = expf(al - funmap(amax[d * H + i])) / (denom[d * H + i] + 1e-16f);
        float v = bf2f(hp[i * 64 + lane]) * w;
        atomicAdd(&op[i * 64 + lane], v);
    }
}

// ---------- relu in place + column sums ----------
__global__ __launch_bounds__(256)
void relu_colsum(float* __restrict__ out, float* __restrict__ colsum)
{
    int t = threadIdx.x;
    int r0 = blockIdx.x * 64;
    float s0 = 0.f, s1 = 0.f;
    for (int k = 0; k < 128; ++k) {
        int idx = k * 256 + t;
        int row = r0 + (idx >> 9);
        int f = idx & 511;              // = t (k even) or t+256 (k odd): race-free
        if (row < N_NODES) {
            size_t off = (size_t)row * D + f;
            float v = out[off];
            v = fmaxf(v, 0.f);
            out[off] = v;
            if (k & 1) s1 += v; else s0 += v;
        }
    }
    atomicAdd(&colsum[t], s0);
    atomicAdd(&colsum[t + 256], s1);
}

// ---------- final semantic softmax + pool + linear ----------
__global__ __launch_bounds__(256)
void finalize(const float* __restrict__ ksum, const float* __restrict__ colsum,
              const float* __restrict__ q_sem, const float* __restrict__ lin_w,
              const float* __restrict__ lin_b, float* __restrict__ dout)
{
    __shared__ float red[256];
    __shared__ float semsh[2];
    int t = threadIdx.x;
    const float invN = 1.0f / (float)N_NODES;
    float p0 = ksum[t] * q_sem[t] + ksum[t + 256] * q_sem[t + 256];
    float p1 = ksum[512 + t] * q_sem[t] + ksum[512 + t + 256] * q_sem[t + 256];

    red[t] = p0; __syncthreads();
    for (int s = 128; s > 0; s >>= 1) { if (t < s) red[t] += red[t + s]; __syncthreads(); }
    float S0 = red[0]; __syncthreads();
    red[t] = p1; __syncthreads();
    for (int s = 128; s > 0; s >>= 1) { if (t < s) red[t] += red[t + s]; __syncthreads(); }
    float S1 = red[0]; __syncthreads();

    if (t == 0) {
        float a0 = S0 * invN, a1 = S1 * invN;
        float mx = fmaxf(a0, a1);
        float e0 = expf(a0 - mx), e1 = expf(a1 - mx);
        semsh[0] = e0 / (e0 + e1);
        semsh[1] = e1 / (e0 + e1);
    }
    __syncthreads();
    float sem0 = semsh[0], sem1 = semsh[1];

    float o0 = 0.f, o1 = 0.f;
    #pragma unroll
    for (int q = 0; q < 2; ++q) {
        int f = t + q * 256;
        float pooled = (sem0 * colsum[f] + sem1 * colsum[512 + f]) * invN;
        o0 += pooled * lin_w[f * 2 + 0];
        o1 += pooled * lin_w[f * 2 + 1];
    }
    red[t] = o0; __syncthreads();
    for (int s = 128; s > 0; s >>= 1) { if (t < s) red[t] += red[t + s]; __syncthreads(); }
    if (t == 0) dout[0] = red[0] + lin_b[0];
    __syncthreads();
    red[t] = o1; __syncthreads();
    for (int s = 128; s > 0; s >>= 1) { if (t < s) red[t] += red[t + s]; __syncthreads(); }
    if (t == 0) dout[1] = red[0] + lin_b[1];
}

extern "C" void kernel_launch(void* const* d_in, const int* in_sizes, int n_in,
                              void* d_out, int out_size, void* d_ws, size_t ws_size,
                              hipStream_t stream)
{
    const float* x_o    = (const float*)d_in[0];
    const float* x_e    = (const float*)d_in[1];
    const int*   e2o    = (const int*)d_in[2];
    const int*   o2o    = (const int*)d_in[3];
    const float* pow_   = (const float*)d_in[4];
    const float* pob    = (const float*)d_in[5];
    const float* pew    = (const float*)d_in[6];
    const float* peb    = (const float*)d_in[7];
    const float* as_e2o = (const float*)d_in[8];
    const float* ad_e2o = (const float*)d_in[9];
    const float* as_o2o = (const float*)d_in[10];
    const float* ad_o2o = (const float*)d_in[11];
    const float* klw    = (const float*)d_in[12];
    const float* klb    = (const float*)d_in[13];
    const float* qsem   = (const float*)d_in[14];
    const float* linw   = (const float*)d_in[15];
    const float* linb   = (const float*)d_in[16];

    char* ws = (char*)d_ws;
    size_t off = 0;
    unsigned short* h_o = (unsigned short*)(ws + off); off += (size_t)N_NODES * D * 2;   // bf16
    unsigned short* h_e = (unsigned short*)(ws + off); off += (size_t)N_NODES * D * 2;   // bf16
    float* outbuf  = (float*)(ws + off); off += (size_t)N_NODES * D * 4;
    float* a_src   = (float*)(ws + off); off += (size_t)N_NODES * H * 4;
    float* a_dst   = (float*)(ws + off); off += (size_t)N_NODES * H * 4;
    unsigned int* amax = (unsigned int*)(ws + off); off += (size_t)N_NODES * H * 4;
    float* denom   = (float*)(ws + off); off += (size_t)N_NODES * H * 4;
    float* colsum  = (float*)(ws + off); off += 2 * 512 * 4;
    float* ksum    = (float*)(ws + off); off += 2 * 512 * 4;

    // zero colsum+ksum (contiguous 2048 floats)
    zero_kernel<<<2, 256, 0, stream>>>((float4*)colsum, 512);

    dim3 gg(D / 64, (N_NODES + 63) / 64);  // x: col tiles (8), y: row tiles (1563)
    gemm_bias_bf16<<<gg, 256, 0, stream>>>(x_o, pow_, pob, h_o, N_NODES);
    gemm_bias_bf16<<<gg, 256, 0, stream>>>(x_e, pew, peb, h_e, N_NODES);

    const int nh_blocks = (N_NODES * H + 255) / 256;
    const int eh_blocks = (N_EDGES * H + 255) / 256;
    const int out_n4 = N_NODES * D / 4;

    for (int m = 0; m < 2; ++m) {
        const unsigned short* hsrc = (m == 0) ? h_e : h_o;
        const int* edges = (m == 0) ? e2o : o2o;
        const float* asw = (m == 0) ? as_e2o : as_o2o;
        const float* adw = (m == 0) ? ad_e2o : ad_o2o;
        const int* srcp = edges;
        const int* dstp = edges + N_EDGES;

        compute_a<<<nh_blocks, 256, 0, stream>>>(hsrc, asw, a_src);
        compute_a<<<nh_blocks, 256, 0, stream>>>(h_o, adw, a_dst);
        init_amax_denom<<<nh_blocks, 256, 0, stream>>>(amax, denom);
        edge_alpha_max<<<eh_blocks, 256, 0, stream>>>(srcp, dstp, a_src, a_dst, amax);
        edge_denom<<<eh_blocks, 256, 0, stream>>>(srcp, dstp, a_src, a_dst, amax, denom);
        zero_kernel<<<(out_n4 + 255) / 256, 256, 0, stream>>>((float4*)outbuf, out_n4);
        edge_scatter<<<N_EDGES / 4, 256, 0, stream>>>(srcp, dstp, a_src, a_dst, amax, denom, hsrc, outbuf);
        relu_colsum<<<(N_NODES + 63) / 64, 256, 0, stream>>>(outbuf, colsum + m * 512);
        gemm_tanh_colsum<<<gg, 256, 0, stream>>>(outbuf, klw, klb, ksum + m * 512, N_NODES);
    }
    finalize<<<1, 256, 0, stream>>>(ksum, colsum, qsem, linw, linb, (float*)d_out);
}

// Round 2
// 2188.060 us; speedup vs baseline: 2.1006x; 2.1006x over previous
//
#include <hip/hip_runtime.h>
#include <math.h>

#define N_NODES 100000
#define N_EDGES 150000
#define D 512
#define H 8
#define DH 64
#define NEG_SLOPE 0.2f
#define LSTR 40   // LDS row stride in bf16 elements (80 B = 20 banks: conflict-free-ish)

typedef __attribute__((ext_vector_type(8))) short bf16x8;
typedef __attribute__((ext_vector_type(4))) float f32x4;

// ---------- helpers ----------
__device__ __forceinline__ float bf2f(unsigned short u) { return __uint_as_float(((unsigned int)u) << 16); }
__device__ __forceinline__ unsigned short f2bf(float f) {
    unsigned int u = __float_as_uint(f);
    unsigned int r = u + 0x7FFFu + ((u >> 16) & 1u);   // round-to-nearest-even
    return (unsigned short)(r >> 16);
}
// pack two fp32 -> two bf16 in one u32 (round-half-up; bias washes out in pooling)
__device__ __forceinline__ unsigned int pkbf(float a, float b) {
    unsigned int ua = __float_as_uint(a) + 0x8000u;
    unsigned int ub = __float_as_uint(b) + 0x8000u;
    return (ua >> 16) | (ub & 0xFFFF0000u);
}
// order-preserving float->u32 map for atomicMax-based segment max
__device__ __forceinline__ unsigned int fmap(float f) {
    unsigned int u = __float_as_uint(f);
    return (u & 0x80000000u) ? ~u : (u | 0x80000000u);
}
__device__ __forceinline__ float funmap(unsigned int m) {
    return __uint_as_float((m & 0x80000000u) ? (m & 0x7FFFFFFFu) : ~m);
}

// ---------- zero fill ----------
__global__ __launch_bounds__(256) void zero_kernel(float4* __restrict__ p, int n4) {
    int t = blockIdx.x * 256 + threadIdx.x;
    if (t < n4) p[t] = make_float4(0.f, 0.f, 0.f, 0.f);
}

// ---------- W[512,512] fp32 -> Wt[n][k] bf16 (transpose + convert) ----------
__global__ __launch_bounds__(256)
void transpose_to_bf16(const float* __restrict__ W, unsigned short* __restrict__ Wt) {
    __shared__ float tile[32][33];
    int bx = blockIdx.x, by = blockIdx.y;
    int t = threadIdx.x, tx = t & 31, ty = t >> 5;
    #pragma unroll
    for (int p = 0; p < 4; ++p) {
        int k = by * 32 + ty + p * 8;
        tile[ty + p * 8][tx] = W[(size_t)k * D + bx * 32 + tx];
    }
    __syncthreads();
    #pragma unroll
    for (int p = 0; p < 4; ++p) {
        int n = bx * 32 + ty + p * 8;
        Wt[(size_t)n * D + by * 32 + tx] = f2bf(tile[tx][ty + p * 8]);
    }
}

// ---------- MFMA GEMM 1: C_bf16[M,512] = A_f32[M,512] @ Bt^T + bias ----------
// Bt is [N=512][K=512] bf16 (pre-transposed weight). 128x128 tile, 4 waves of 64x64.
__global__ __launch_bounds__(256)
void mfma_gemm_f32a(const float* __restrict__ A, const unsigned short* __restrict__ Bt,
                    const float* __restrict__ bias, unsigned short* __restrict__ C, int M)
{
    __shared__ __align__(16) unsigned short As[128 * LSTR];
    __shared__ __align__(16) unsigned short Bs[128 * LSTR];
    const int tid = threadIdx.x;
    const int lane = tid & 63;
    const int wave = tid >> 6;
    const int rb = blockIdx.y * 128, cb = blockIdx.x * 128;
    const int wm = (wave >> 1) * 64, wn = (wave & 1) * 64;

    // A staging: 128 rows x 32 f32 = 1024 float4 chunks; 4 per thread (8 lanes/row: coalesced 128B)
    const float* ap[4]; unsigned short* aw[4];
    #pragma unroll
    for (int it = 0; it < 4; ++it) {
        int chunk = it * 256 + tid;
        int r = chunk >> 3, c = chunk & 7;
        int rg = rb + r; if (rg > M - 1) rg = M - 1;
        ap[it] = A + (size_t)rg * D + c * 4;
        aw[it] = &As[r * LSTR + c * 4];
    }
    // B staging: 128 rows x 32 bf16 = 512 x 16B chunks; 2 per thread
    const unsigned short* bp[2]; unsigned short* bw[2];
    #pragma unroll
    for (int it = 0; it < 2; ++it) {
        int q = it * 256 + tid;
        int n = q >> 2, c = q & 3;
        bp[it] = Bt + (size_t)(cb + n) * D + c * 8;
        bw[it] = &Bs[n * LSTR + c * 8];
    }

    f32x4 acc[4][4];
    #pragma unroll
    for (int i = 0; i < 4; ++i)
        #pragma unroll
        for (int j = 0; j < 4; ++j) acc[i][j] = (f32x4){0.f, 0.f, 0.f, 0.f};

    const int fro = (lane & 15) * LSTR + (lane >> 4) * 8;

    for (int k0 = 0; k0 < D; k0 += 32) {
        float4 av[4]; uint4 bv[2];
        #pragma unroll
        for (int it = 0; it < 4; ++it) av[it] = *(const float4*)(ap[it] + k0);
        #pragma unroll
        for (int it = 0; it < 2; ++it) bv[it] = *(const uint4*)(bp[it] + k0);
        __syncthreads();
        #pragma unroll
        for (int it = 0; it < 4; ++it) {
            uint2 p; p.x = pkbf(av[it].x, av[it].y); p.y = pkbf(av[it].z, av[it].w);
            *(uint2*)aw[it] = p;
        }
        #pragma unroll
        for (int it = 0; it < 2; ++it) *(uint4*)bw[it] = bv[it];
        __syncthreads();
        bf16x8 af[4], bfr[4];
        #pragma unroll
        for (int mi = 0; mi < 4; ++mi) af[mi] = *(const bf16x8*)&As[(wm + mi * 16) * LSTR + fro];
        #pragma unroll
        for (int ni = 0; ni < 4; ++ni) bfr[ni] = *(const bf16x8*)&Bs[(wn + ni * 16) * LSTR + fro];
        #pragma unroll
        for (int mi = 0; mi < 4; ++mi)
            #pragma unroll
            for (int ni = 0; ni < 4; ++ni)
                acc[mi][ni] = __builtin_amdgcn_mfma_f32_16x16x32_bf16(af[mi], bfr[ni], acc[mi][ni], 0, 0, 0);
    }

    float bb[4];
    #pragma unroll
    for (int ni = 0; ni < 4; ++ni) bb[ni] = bias[cb + wn + ni * 16 + (lane & 15)];
    #pragma unroll
    for (int mi = 0; mi < 4; ++mi) {
        int rg0 = rb + wm + mi * 16 + (lane >> 4) * 4;
        #pragma unroll
        for (int r = 0; r < 4; ++r) {
            int rg = rg0 + r;
            if (rg < M) {
                size_t base = (size_t)rg * D + cb + wn + (lane & 15);
                #pragma unroll
                for (int ni = 0; ni < 4; ++ni)
                    C[base + ni * 16] = f2bf(acc[mi][ni][r] + bb[ni]);
            }
        }
    }
}

// ---------- MFMA GEMM 2: ksum[f] += sum_rows tanh( (A_bf16 @ Bt^T + bias)[row,f] ) ----------
__global__ __launch_bounds__(256)
void mfma_gemm_bf16a_tanhsum(const unsigned short* __restrict__ A, const unsigned short* __restrict__ Bt,
                             const float* __restrict__ bias, float* __restrict__ ksum, int M)
{
    __shared__ __align__(16) unsigned short As[128 * LSTR];
    __shared__ __align__(16) unsigned short Bs[128 * LSTR];
    const int tid = threadIdx.x;
    const int lane = tid & 63;
    const int wave = tid >> 6;
    const int rb = blockIdx.y * 128, cb = blockIdx.x * 128;
    const int wm = (wave >> 1) * 64, wn = (wave & 1) * 64;

    const unsigned short *ap[2], *bp[2]; unsigned short *aw[2], *bw[2];
    #pragma unroll
    for (int it = 0; it < 2; ++it) {
        int q = it * 256 + tid;
        int r = q >> 2, c = q & 3;
        int rg = rb + r; if (rg > M - 1) rg = M - 1;
        ap[it] = A + (size_t)rg * D + c * 8;
        aw[it] = &As[r * LSTR + c * 8];
        bp[it] = Bt + (size_t)(cb + r) * D + c * 8;
        bw[it] = &Bs[r * LSTR + c * 8];
    }

    f32x4 acc[4][4];
    #pragma unroll
    for (int i = 0; i < 4; ++i)
        #pragma unroll
        for (int j = 0; j < 4; ++j) acc[i][j] = (f32x4){0.f, 0.f, 0.f, 0.f};

    const int fro = (lane & 15) * LSTR + (lane >> 4) * 8;

    for (int k0 = 0; k0 < D; k0 += 32) {
        uint4 av[2], bv[2];
        #pragma unroll
        for (int it = 0; it < 2; ++it) { av[it] = *(const uint4*)(ap[it] + k0); bv[it] = *(const uint4*)(bp[it] + k0); }
        __syncthreads();
        #pragma unroll
        for (int it = 0; it < 2; ++it) { *(uint4*)aw[it] = av[it]; *(uint4*)bw[it] = bv[it]; }
        __syncthreads();
        bf16x8 af[4], bfr[4];
        #pragma unroll
        for (int mi = 0; mi < 4; ++mi) af[mi] = *(const bf16x8*)&As[(wm + mi * 16) * LSTR + fro];
        #pragma unroll
        for (int ni = 0; ni < 4; ++ni) bfr[ni] = *(const bf16x8*)&Bs[(wn + ni * 16) * LSTR + fro];
        #pragma unroll
        for (int mi = 0; mi < 4; ++mi)
            #pragma unroll
            for (int ni = 0; ni < 4; ++ni)
                acc[mi][ni] = __builtin_amdgcn_mfma_f32_16x16x32_bf16(af[mi], bfr[ni], acc[mi][ni], 0, 0, 0);
    }

    float bb[4];
    #pragma unroll
    for (int ni = 0; ni < 4; ++ni) bb[ni] = bias[cb + wn + ni * 16 + (lane & 15)];
    float cs[4] = {0.f, 0.f, 0.f, 0.f};
    #pragma unroll
    for (int mi = 0; mi < 4; ++mi) {
        int rg0 = rb + wm + mi * 16 + (lane >> 4) * 4;
        #pragma unroll
        for (int r = 0; r < 4; ++r) {
            int rg = rg0 + r;
            if (rg < M) {
                #pragma unroll
                for (int ni = 0; ni < 4; ++ni)
                    cs[ni] += tanhf(acc[mi][ni][r] + bb[ni]);
            }
        }
    }
    __syncthreads();
    float* red = (float*)As;
    if (tid < 128) red[tid] = 0.f;
    __syncthreads();
    #pragma unroll
    for (int ni = 0; ni < 4; ++ni) atomicAdd(&red[wn + ni * 16 + (lane & 15)], cs[ni]);
    __syncthreads();
    if (tid < 128) atomicAdd(&ksum[cb + tid], red[tid]);
}

// ---------- a[n,h] = sum_d h[n,h,d] * att[h,d]  (h in bf16) ----------
__global__ __launch_bounds__(256)
void compute_a(const unsigned short* __restrict__ h, const float* __restrict__ att,
               float* __restrict__ a)
{
    int t = blockIdx.x * 256 + threadIdx.x;
    if (t >= N_NODES * H) return;
    int n = t >> 3, hh = t & 7;
    const uint4* hp = (const uint4*)(h + (size_t)n * D + hh * DH);
    const float4* apt = (const float4*)(att + hh * DH);
    float s = 0.f;
    #pragma unroll
    for (int q = 0; q < 8; ++q) {
        uint4 u = hp[q];
        float4 w0 = apt[q * 2], w1 = apt[q * 2 + 1];
        s += bf2f((unsigned short)(u.x & 0xFFFF)) * w0.x + bf2f((unsigned short)(u.x >> 16)) * w0.y
           + bf2f((unsigned short)(u.y & 0xFFFF)) * w0.z + bf2f((unsigned short)(u.y >> 16)) * w0.w
           + bf2f((unsigned short)(u.z & 0xFFFF)) * w1.x + bf2f((unsigned short)(u.z >> 16)) * w1.y
           + bf2f((unsigned short)(u.w & 0xFFFF)) * w1.z + bf2f((unsigned short)(u.w >> 16)) * w1.w;
    }
    a[t] = s;
}

// ---------- init amax (-inf, mapped) and denom (0) ----------
__global__ __launch_bounds__(256)
void init_amax_denom(unsigned int* __restrict__ amax, float* __restrict__ denom)
{
    int t = blockIdx.x * 256 + threadIdx.x;
    if (t < N_NODES * H) { amax[t] = 0x007FFFFFu; denom[t] = 0.f; }
}

// ---------- per-edge alpha -> segment max ----------
__global__ __launch_bounds__(256)
void edge_alpha_max(const int* __restrict__ src, const int* __restrict__ dst,
                    const float* __restrict__ a_src, const float* __restrict__ a_dst,
                    unsigned int* __restrict__ amax)
{
    int t = blockIdx.x * 256 + threadIdx.x;
    if (t >= N_EDGES * H) return;
    int e = t >> 3, hh = t & 7;
    int s = src[e], d = dst[e];
    float al = a_src[s * H + hh] + a_dst[d * H + hh];
    al = (al >= 0.f) ? al : NEG_SLOPE * al;
    atomicMax(&amax[d * H + hh], fmap(al));
}

// ---------- per-edge exp -> segment sum ----------
__global__ __launch_bounds__(256)
void edge_denom(const int* __restrict__ src, const int* __restrict__ dst,
                const float* __restrict__ a_src, const float* __restrict__ a_dst,
                const unsigned int* __restrict__ amax, float* __restrict__ denom)
{
    int t = blockIdx.x * 256 + threadIdx.x;
    if (t >= N_EDGES * H) return;
    int e = t >> 3, hh = t & 7;
    int s = src[e], d = dst[e];
    float al = a_src[s * H + hh] + a_dst[d * H + hh];
    al = (al >= 0.f) ? al : NEG_SLOPE * al;
    atomicAdd(&denom[d * H + hh], expf(al - funmap(amax[d * H + hh])));
}

// ---------- message scatter: one wave per edge ----------
__global__ __launch_bounds__(256)
void edge_scatter(const int* __restrict__ src, const int* __restrict__ dst,
                  const float* __restrict__ a_src, const float* __restrict__ a_dst,
                  const unsigned int* __restrict__ amax, const float* __restrict__ denom,
                  const unsigned short* __restrict__ h_src, float* __restrict__ out)
{
    int e = (blockIdx.x * 256 + threadIdx.x) >> 6;
    int lane = threadIdx.x & 63;
    if (e >= N_EDGES) return;
    int s = src[e], d = dst[e];
    const unsigned short* hp = h_src + (size_t)s * D;
    float* op = out + (size_t)d * D;
    #pragma unroll
    for (int i = 0; i < H; ++i) {
        float al = a_src[s * H + i] + a_dst[d * H + i];
        al = (al >= 0.f) ? al : NEG_SLOPE * al;
        float w = expf(al - funmap(amax[d * H + i])) / (denom[d * H + i] + 1e-16f);
        float v = bf2f(hp[i * 64 + lane]) * w;
        atomicAdd(&op[i * 64 + lane], v);
    }
}

// ---------- relu -> bf16 copy + column sums ----------
__global__ __launch_bounds__(256)
void relu_colsum_bf16(const float* __restrict__ out, unsigned short* __restrict__ outbf,
                      float* __restrict__ colsum)
{
    __shared__ float red[512];
    int t = threadIdx.x;
    int r0 = blockIdx.x * 128;
    int c4 = t & 127;   // fixed float4-column per thread
    float s[4] = {0.f, 0.f, 0.f, 0.f};
    for (int it = 0; it < 64; ++it) {
        int idx = it * 256 + t;
        int row = r0 + (idx >> 7);
        if (row < N_NODES) {
            float4 v = *((const float4*)(out + (size_t)row * D) + c4);
            v.x = fmaxf(v.x, 0.f); v.y = fmaxf(v.y, 0.f);
            v.z = fmaxf(v.z, 0.f); v.w = fmaxf(v.w, 0.f);
            uint2 pk; pk.x = pkbf(v.x, v.y); pk.y = pkbf(v.z, v.w);
            *((uint2*)(outbf + (size_t)row * D) + c4) = pk;
            s[0] += v.x; s[1] += v.y; s[2] += v.z; s[3] += v.w;
        }
    }
    red[t] = 0.f; red[t + 256] = 0.f;
    __syncthreads();
    #pragma unroll
    for (int j = 0; j < 4; ++j) atomicAdd(&red[c4 * 4 + j], s[j]);
    __syncthreads();
    atomicAdd(&colsum[t], red[t]);
    atomicAdd(&colsum[t + 256], red[t + 256]);
}

// ---------- final semantic softmax + pool + linear ----------
__global__ __launch_bounds__(256)
void finalize(const float* __restrict__ ksum, const float* __restrict__ colsum,
              const float* __restrict__ q_sem, const float* __restrict__ lin_w,
              const float* __restrict__ lin_b, float* __restrict__ dout)
{
    __shared__ float red[256];
    __shared__ float semsh[2];
    int t = threadIdx.x;
    const float invN = 1.0f / (float)N_NODES;
    float p0 = ksum[t] * q_sem[t] + ksum[t + 256] * q_sem[t + 256];
    float p1 = ksum[512 + t] * q_sem[t] + ksum[512 + t + 256] * q_sem[t + 256];

    red[t] = p0; __syncthreads();
    for (int s = 128; s > 0; s >>= 1) { if (t < s) red[t] += red[t + s]; __syncthreads(); }
    float S0 = red[0]; __syncthreads();
    red[t] = p1; __syncthreads();
    for (int s = 128; s > 0; s >>= 1) { if (t < s) red[t] += red[t + s]; __syncthreads(); }
    float S1 = red[0]; __syncthreads();

    if (t == 0) {
        float a0 = S0 * invN, a1 = S1 * invN;
        float mx = fmaxf(a0, a1);
        float e0 = expf(a0 - mx), e1 = expf(a1 - mx);
        semsh[0] = e0 / (e0 + e1);
        semsh[1] = e1 / (e0 + e1);
    }
    __syncthreads();
    float sem0 = semsh[0], sem1 = semsh[1];

    float o0 = 0.f, o1 = 0.f;
    #pragma unroll
    for (int q = 0; q < 2; ++q) {
        int f = t + q * 256;
        float pooled = (sem0 * colsum[f] + sem1 * colsum[512 + f]) * invN;
        o0 += pooled * lin_w[f * 2 + 0];
        o1 += pooled * lin_w[f * 2 + 1];
    }
    red[t] = o0; __syncthreads();
    for (int s = 128; s > 0; s >>= 1) { if (t < s) red[t] += red[t + s]; __syncthreads(); }
    if (t == 0) dout[0] = red[0] + lin_b[0];
    __syncthreads();
    red[t] = o1; __syncthreads();
    for (int s = 128; s > 0; s >>= 1) { if (t < s) red[t] += red[t + s]; __syncthreads(); }
    if (t == 0) dout[1] = red[0] + lin_b[1];
}

extern "C" void kernel_launch(void* const* d_in, const int* in_sizes, int n_in,
                              void* d_out, int out_size, void* d_ws, size_t ws_size,
                              hipStream_t stream)
{
    const float* x_o    = (const float*)d_in[0];
    const float* x_e    = (const float*)d_in[1];
    const int*   e2o    = (const int*)d_in[2];
    const int*   o2o    = (const int*)d_in[3];
    const float* pow_   = (const float*)d_in[4];
    const float* pob    = (const float*)d_in[5];
    const float* pew    = (const float*)d_in[6];
    const float* peb    = (const float*)d_in[7];
    const float* as_e2o = (const float*)d_in[8];
    const float* ad_e2o = (const float*)d_in[9];
    const float* as_o2o = (const float*)d_in[10];
    const float* ad_o2o = (const float*)d_in[11];
    const float* klw    = (const float*)d_in[12];
    const float* klb    = (const float*)d_in[13];
    const float* qsem   = (const float*)d_in[14];
    const float* linw   = (const float*)d_in[15];
    const float* linb   = (const float*)d_in[16];

    char* ws = (char*)d_ws;
    size_t off = 0;
    unsigned short* h_o   = (unsigned short*)(ws + off); off += (size_t)N_NODES * D * 2;
    unsigned short* h_e   = (unsigned short*)(ws + off); off += (size_t)N_NODES * D * 2;
    float* outbuf         = (float*)(ws + off);          off += (size_t)N_NODES * D * 4;
    unsigned short* outbf = (unsigned short*)(ws + off); off += (size_t)N_NODES * D * 2;
    float* a_src          = (float*)(ws + off);          off += (size_t)N_NODES * H * 4;
    float* a_dst          = (float*)(ws + off);          off += (size_t)N_NODES * H * 4;
    unsigned int* amax    = (unsigned int*)(ws + off);   off += (size_t)N_NODES * H * 4;
    float* denom          = (float*)(ws + off);          off += (size_t)N_NODES * H * 4;
    float* colsum         = (float*)(ws + off);          off += 2 * 512 * 4;
    float* ksum           = (float*)(ws + off);          off += 2 * 512 * 4;
    unsigned short* wt_po = (unsigned short*)(ws + off); off += (size_t)D * D * 2;
    unsigned short* wt_pe = (unsigned short*)(ws + off); off += (size_t)D * D * 2;
    unsigned short* wt_kl = (unsigned short*)(ws + off); off += (size_t)D * D * 2;

    // zero colsum+ksum (contiguous 2048 floats)
    zero_kernel<<<2, 256, 0, stream>>>((float4*)colsum, 512);

    // pre-transpose+convert the three 512x512 weights to bf16 W^T
    dim3 tg(16, 16);
    transpose_to_bf16<<<tg, 256, 0, stream>>>(pow_, wt_po);
    transpose_to_bf16<<<tg, 256, 0, stream>>>(pew, wt_pe);
    transpose_to_bf16<<<tg, 256, 0, stream>>>(klw, wt_kl);

    dim3 gg(D / 128, (N_NODES + 127) / 128);   // 4 x 782
    mfma_gemm_f32a<<<gg, 256, 0, stream>>>(x_o, wt_po, pob, h_o, N_NODES);
    mfma_gemm_f32a<<<gg, 256, 0, stream>>>(x_e, wt_pe, peb, h_e, N_NODES);

    const int nh_blocks = (N_NODES * H + 255) / 256;
    const int eh_blocks = (N_EDGES * H + 255) / 256;
    const int out_n4 = N_NODES * D / 4;

    for (int m = 0; m < 2; ++m) {
        const unsigned short* hsrc = (m == 0) ? h_e : h_o;
        const int* edges = (m == 0) ? e2o : o2o;
        const float* asw = (m == 0) ? as_e2o : as_o2o;
        const float* adw = (m == 0) ? ad_e2o : ad_o2o;
        const int* srcp = edges;
        const int* dstp = edges + N_EDGES;

        compute_a<<<nh_blocks, 256, 0, stream>>>(hsrc, asw, a_src);
        compute_a<<<nh_blocks, 256, 0, stream>>>(h_o, adw, a_dst);
        init_amax_denom<<<nh_blocks, 256, 0, stream>>>(amax, denom);
        edge_alpha_max<<<eh_blocks, 256, 0, stream>>>(srcp, dstp, a_src, a_dst, amax);
        edge_denom<<<eh_blocks, 256, 0, stream>>>(srcp, dstp, a_src, a_dst, amax, denom);
        zero_kernel<<<(out_n4 + 255) / 256, 256, 0, stream>>>((float4*)outbuf, out_n4);
        edge_scatter<<<N_EDGES / 4, 256, 0, stream>>>(srcp, dstp, a_src, a_dst, amax, denom, hsrc, outbuf);
        relu_colsum_bf16<<<(N_NODES + 127) / 128, 256, 0, stream>>>(outbuf, outbf, colsum + m * 512);
        mfma_gemm_bf16a_tanhsum<<<gg, 256, 0, stream>>>(outbf, wt_kl, klb, ksum + m * 512, N_NODES);
    }
    finalize<<<1, 256, 0, stream>>>(ksum, colsum, qsem, linw, linb, (float*)d_out);
}

// Round 3
// 1278.136 us; speedup vs baseline: 3.5961x; 1.7119x over previous
//
#include <hip/hip_runtime.h>
#include <math.h>

#define N_NODES 100000
#define N_EDGES 150000
#define D 512
#define H 8
#define NEG_SLOPE 0.2f

typedef __attribute__((ext_vector_type(8))) short bf16x8;
typedef __attribute__((ext_vector_type(4))) float f32x4;

// ---------- helpers ----------
__device__ __forceinline__ float bf2f(unsigned short u) { return __uint_as_float(((unsigned int)u) << 16); }
__device__ __forceinline__ unsigned short f2bf(float f) {
    unsigned int u = __float_as_uint(f);
    unsigned int r = u + 0x7FFFu + ((u >> 16) & 1u);
    return (unsigned short)(r >> 16);
}
__device__ __forceinline__ unsigned int pkbf(float a, float b) {
    unsigned int ua = __float_as_uint(a) + 0x8000u;
    unsigned int ub = __float_as_uint(b) + 0x8000u;
    return (ua >> 16) | (ub & 0xFFFF0000u);
}
// async global->LDS, 16B per lane; lds ptr must be wave-uniform base (lane*16 implicit)
__device__ __forceinline__ void gl_lds16(const void* g, void* l) {
    __builtin_amdgcn_global_load_lds((const __attribute__((address_space(1))) void*)g,
                                     (__attribute__((address_space(3))) void*)l, 16, 0, 0);
}

// ---------- zero fill ----------
__global__ __launch_bounds__(256) void zero_kernel(float4* __restrict__ p, int n4) {
    int t = blockIdx.x * 256 + threadIdx.x;
    if (t < n4) p[t] = make_float4(0.f, 0.f, 0.f, 0.f);
}

// ---------- W[512,512] fp32 -> Wt[n][k] bf16 ----------
__global__ __launch_bounds__(256)
void transpose_to_bf16(const float* __restrict__ W, unsigned short* __restrict__ Wt) {
    __shared__ float tile[32][33];
    int bx = blockIdx.x, by = blockIdx.y;
    int t = threadIdx.x, tx = t & 31, ty = t >> 5;
    #pragma unroll
    for (int p = 0; p < 4; ++p) {
        int k = by * 32 + ty + p * 8;
        tile[ty + p * 8][tx] = W[(size_t)k * D + bx * 32 + tx];
    }
    __syncthreads();
    #pragma unroll
    for (int p = 0; p < 4; ++p) {
        int n = bx * 32 + ty + p * 8;
        Wt[(size_t)n * D + by * 32 + tx] = f2bf(tile[tx][ty + p * 8]);
    }
}

// ---------- CSR build ----------
__global__ __launch_bounds__(256)
void hist_edges(const int* __restrict__ e2o, const int* __restrict__ o2o, int* __restrict__ deg) {
    int i = blockIdx.x * 256 + threadIdx.x;
    if (i < N_EDGES) atomicAdd(&deg[e2o[N_EDGES + i]], 1);
    else if (i < 2 * N_EDGES) atomicAdd(&deg[N_NODES + o2o[N_EDGES + (i - N_EDGES)]], 1);
}

__global__ __launch_bounds__(256)
void scan1(const int* __restrict__ deg, int* __restrict__ rowptr, int* __restrict__ partials, int n) {
    __shared__ int lds[256];
    int t = threadIdx.x, b = blockIdx.x;
    int base = b * 1024 + t * 4;
    int d0 = (base + 0 < n) ? deg[base + 0] : 0;
    int d1 = (base + 1 < n) ? deg[base + 1] : 0;
    int d2 = (base + 2 < n) ? deg[base + 2] : 0;
    int d3 = (base + 3 < n) ? deg[base + 3] : 0;
    int s = d0 + d1 + d2 + d3;
    lds[t] = s;
    __syncthreads();
    for (int off = 1; off < 256; off <<= 1) {
        int v = (t >= off) ? lds[t - off] : 0;
        __syncthreads();
        lds[t] += v;
        __syncthreads();
    }
    int incl = lds[t];
    int eb = incl - s;
    if (base + 0 < n) rowptr[base + 0] = eb;
    if (base + 1 < n) rowptr[base + 1] = eb + d0;
    if (base + 2 < n) rowptr[base + 2] = eb + d0 + d1;
    if (base + 3 < n) rowptr[base + 3] = eb + d0 + d1 + d2;
    if (t == 255) partials[b] = incl;
}

__global__ __launch_bounds__(256)
void scan2(int* __restrict__ partials, int nb) {
    __shared__ int lds[256];
    int t = threadIdx.x;
    lds[t] = (t < nb) ? partials[t] : 0;
    __syncthreads();
    if (t == 0) {
        int acc = 0;
        for (int i = 0; i < nb; ++i) { int v = lds[i]; lds[i] = acc; acc += v; }
    }
    __syncthreads();
    if (t < nb) partials[t] = lds[t];
}

__global__ __launch_bounds__(256)
void scan3(int* __restrict__ rowptr, const int* __restrict__ partials, int* __restrict__ cursor, int n, int total) {
    int t = threadIdx.x, b = blockIdx.x;
    int base = b * 1024 + t * 4;
    int add = partials[b];
    #pragma unroll
    for (int j = 0; j < 4; ++j) {
        if (base + j < n) {
            int v = rowptr[base + j] + add;
            rowptr[base + j] = v;
            cursor[base + j] = v;
        }
    }
    if (b == 0 && t == 0) rowptr[n] = total;
}

__global__ __launch_bounds__(256)
void fill_csr(const int* __restrict__ e2o, const int* __restrict__ o2o,
              int* __restrict__ cursor, int* __restrict__ csr) {
    int i = blockIdx.x * 256 + threadIdx.x;
    if (i < N_EDGES) {
        int d = e2o[N_EDGES + i];
        int p = atomicAdd(&cursor[d], 1);
        csr[p] = e2o[i];
    } else if (i < 2 * N_EDGES) {
        int j = i - N_EDGES;
        int d = o2o[N_EDGES + j];
        int p = atomicAdd(&cursor[N_NODES + d], 1);
        csr[p] = o2o[j];
    }
}

// ---------- MFMA GEMM 1: C_bf16[M,512] = A_f32[M,512] @ Bt^T + bias ----------
__global__ __launch_bounds__(256)
void gemm_proj(const float* __restrict__ A, const unsigned short* __restrict__ Bt,
               const float* __restrict__ bias, unsigned short* __restrict__ C, int M)
{
    __shared__ __align__(16) float As32[128 * 32];
    __shared__ __align__(16) unsigned short Bs[128 * 32];
    const int tid = threadIdx.x, lane = tid & 63, wave = tid >> 6;
    const int rb = blockIdx.y * 128, cb = blockIdx.x * 128;
    const int wm = (wave >> 1) * 64, wn = (wave & 1) * 64;

    // A: fp32 tile 128x32 = 16KB = 16 wave-loads; 4 calls/wave, 8 rows each
    const float* agp[4]; float* alp[4];
    #pragma unroll
    for (int c = 0; c < 4; ++c) {
        int r = c * 32 + wave * 8 + (lane >> 3);
        int rg = rb + r; if (rg > M - 1) rg = M - 1;
        agp[c] = A + (size_t)rg * D + (lane & 7) * 4;
        alp[c] = &As32[(c * 32 + wave * 8) * 32];
    }
    // B: bf16 tile 128x32 = 8KB; 2 calls/wave, 16 rows each
    const unsigned short* bgp[2]; unsigned short* blp[2];
    #pragma unroll
    for (int c = 0; c < 2; ++c) {
        int r = c * 64 + wave * 16 + (lane >> 2);
        bgp[c] = Bt + (size_t)(cb + r) * D + (lane & 3) * 8;
        blp[c] = &Bs[(c * 64 + wave * 16) * 32];
    }

    f32x4 acc[4][4];
    #pragma unroll
    for (int i = 0; i < 4; ++i)
        #pragma unroll
        for (int j = 0; j < 4; ++j) acc[i][j] = (f32x4){0.f, 0.f, 0.f, 0.f};

    const int fro = (lane & 15) * 32 + (lane >> 4) * 8;

    for (int k = 0; k < 16; ++k) {
        if (k) __syncthreads();
        #pragma unroll
        for (int c = 0; c < 4; ++c) { gl_lds16(agp[c], alp[c]); agp[c] += 32; }
        #pragma unroll
        for (int c = 0; c < 2; ++c) { gl_lds16(bgp[c], blp[c]); bgp[c] += 32; }
        __syncthreads();
        bf16x8 af[4], bfr[4];
        #pragma unroll
        for (int mi = 0; mi < 4; ++mi) {
            const float* ar = &As32[(wm + mi * 16 + (lane & 15)) * 32 + (lane >> 4) * 8];
            float4 u0 = *(const float4*)ar;
            float4 u1 = *(const float4*)(ar + 4);
            union { bf16x8 v; unsigned int u[4]; } cv;
            cv.u[0] = pkbf(u0.x, u0.y); cv.u[1] = pkbf(u0.z, u0.w);
            cv.u[2] = pkbf(u1.x, u1.y); cv.u[3] = pkbf(u1.z, u1.w);
            af[mi] = cv.v;
        }
        #pragma unroll
        for (int ni = 0; ni < 4; ++ni) bfr[ni] = *(const bf16x8*)&Bs[(wn + ni * 16) * 32 + fro];
        #pragma unroll
        for (int mi = 0; mi < 4; ++mi)
            #pragma unroll
            for (int ni = 0; ni < 4; ++ni)
                acc[mi][ni] = __builtin_amdgcn_mfma_f32_16x16x32_bf16(af[mi], bfr[ni], acc[mi][ni], 0, 0, 0);
    }

    float bb[4];
    #pragma unroll
    for (int ni = 0; ni < 4; ++ni) bb[ni] = bias[cb + wn + ni * 16 + (lane & 15)];
    #pragma unroll
    for (int mi = 0; mi < 4; ++mi) {
        int rg0 = rb + wm + mi * 16 + (lane >> 4) * 4;
        #pragma unroll
        for (int r = 0; r < 4; ++r) {
            int rg = rg0 + r;
            if (rg < M) {
                size_t base = (size_t)rg * D + cb + wn + (lane & 15);
                #pragma unroll
                for (int ni = 0; ni < 4; ++ni)
                    C[base + ni * 16] = f2bf(acc[mi][ni][r] + bb[ni]);
            }
        }
    }
}

// ---------- MFMA GEMM 2: ksum[f] += sum_rows tanh( (A_bf16 @ Bt^T + bias)[row,f] ) ----------
__global__ __launch_bounds__(256)
void gemm_tanh(const unsigned short* __restrict__ A, const unsigned short* __restrict__ Bt,
               const float* __restrict__ bias, float* __restrict__ ksum, int M)
{
    __shared__ __align__(16) unsigned short As[128 * 32];
    __shared__ __align__(16) unsigned short Bs[128 * 32];
    const int tid = threadIdx.x, lane = tid & 63, wave = tid >> 6;
    const int rb = blockIdx.y * 128, cb = blockIdx.x * 128;
    const int wm = (wave >> 1) * 64, wn = (wave & 1) * 64;

    const unsigned short* agp[2]; unsigned short* alp[2];
    const unsigned short* bgp[2]; unsigned short* blp[2];
    #pragma unroll
    for (int c = 0; c < 2; ++c) {
        int r = c * 64 + wave * 16 + (lane >> 2);
        int rg = rb + r; if (rg > M - 1) rg = M - 1;
        agp[c] = A + (size_t)rg * D + (lane & 3) * 8;
        alp[c] = &As[(c * 64 + wave * 16) * 32];
        bgp[c] = Bt + (size_t)(cb + r) * D + (lane & 3) * 8;
        blp[c] = &Bs[(c * 64 + wave * 16) * 32];
    }

    f32x4 acc[4][4];
    #pragma unroll
    for (int i = 0; i < 4; ++i)
        #pragma unroll
        for (int j = 0; j < 4; ++j) acc[i][j] = (f32x4){0.f, 0.f, 0.f, 0.f};

    const int fro = (lane & 15) * 32 + (lane >> 4) * 8;

    for (int k = 0; k < 16; ++k) {
        if (k) __syncthreads();
        #pragma unroll
        for (int c = 0; c < 2; ++c) {
            gl_lds16(agp[c], alp[c]); agp[c] += 32;
            gl_lds16(bgp[c], blp[c]); bgp[c] += 32;
        }
        __syncthreads();
        bf16x8 af[4], bfr[4];
        #pragma unroll
        for (int mi = 0; mi < 4; ++mi) af[mi] = *(const bf16x8*)&As[(wm + mi * 16) * 32 + fro];
        #pragma unroll
        for (int ni = 0; ni < 4; ++ni) bfr[ni] = *(const bf16x8*)&Bs[(wn + ni * 16) * 32 + fro];
        #pragma unroll
        for (int mi = 0; mi < 4; ++mi)
            #pragma unroll
            for (int ni = 0; ni < 4; ++ni)
                acc[mi][ni] = __builtin_amdgcn_mfma_f32_16x16x32_bf16(af[mi], bfr[ni], acc[mi][ni], 0, 0, 0);
    }

    float bb[4];
    #pragma unroll
    for (int ni = 0; ni < 4; ++ni) bb[ni] = bias[cb + wn + ni * 16 + (lane & 15)];
    float cs[4] = {0.f, 0.f, 0.f, 0.f};
    #pragma unroll
    for (int mi = 0; mi < 4; ++mi) {
        int rg0 = rb + wm + mi * 16 + (lane >> 4) * 4;
        #pragma unroll
        for (int r = 0; r < 4; ++r) {
            int rg = rg0 + r;
            if (rg < M) {
                #pragma unroll
                for (int ni = 0; ni < 4; ++ni)
                    cs[ni] += tanhf(acc[mi][ni][r] + bb[ni]);
            }
        }
    }
    __syncthreads();
    float* red = (float*)As;
    if (tid < 128) red[tid] = 0.f;
    __syncthreads();
    #pragma unroll
    for (int ni = 0; ni < 4; ++ni) atomicAdd(&red[wn + ni * 16 + (lane & 15)], cs[ni]);
    __syncthreads();
    if (tid < 128) atomicAdd(&ksum[cb + tid], red[tid]);
}

// ---------- a-vectors: up to 3 dots per node sharing one h read ----------
__global__ __launch_bounds__(256)
void compute_a3(const unsigned short* __restrict__ h, const float* __restrict__ att0,
                const float* __restrict__ att1, const float* __restrict__ att2,
                float* __restrict__ a0, float* __restrict__ a1, float* __restrict__ a2,
                int natt)
{
    int t = blockIdx.x * 256 + threadIdx.x;
    if (t >= N_NODES * H) return;
    int n = t >> 3, hh = t & 7;
    const uint4* hp = (const uint4*)(h + (size_t)n * D + hh * 64);
    const float4* p0 = (const float4*)(att0 + hh * 64);
    const float4* p1 = (const float4*)(att1 + hh * 64);
    const float4* p2 = (const float4*)(att2 + hh * 64);
    float s0 = 0.f, s1 = 0.f, s2 = 0.f;
    #pragma unroll
    for (int q = 0; q < 8; ++q) {
        uint4 u = hp[q];
        float f0 = bf2f((unsigned short)(u.x & 0xFFFF)), f1 = bf2f((unsigned short)(u.x >> 16));
        float f2 = bf2f((unsigned short)(u.y & 0xFFFF)), f3 = bf2f((unsigned short)(u.y >> 16));
        float f4 = bf2f((unsigned short)(u.z & 0xFFFF)), f5 = bf2f((unsigned short)(u.z >> 16));
        float f6 = bf2f((unsigned short)(u.w & 0xFFFF)), f7 = bf2f((unsigned short)(u.w >> 16));
        float4 wa = p0[2 * q], wb = p0[2 * q + 1];
        s0 += f0 * wa.x + f1 * wa.y + f2 * wa.z + f3 * wa.w + f4 * wb.x + f5 * wb.y + f6 * wb.z + f7 * wb.w;
        if (natt > 1) {
            wa = p1[2 * q]; wb = p1[2 * q + 1];
            s1 += f0 * wa.x + f1 * wa.y + f2 * wa.z + f3 * wa.w + f4 * wb.x + f5 * wb.y + f6 * wb.z + f7 * wb.w;
        }
        if (natt > 2) {
            wa = p2[2 * q]; wb = p2[2 * q + 1];
            s2 += f0 * wa.x + f1 * wa.y + f2 * wa.z + f3 * wa.w + f4 * wb.x + f5 * wb.y + f6 * wb.z + f7 * wb.w;
        }
    }
    a0[t] = s0;
    if (natt > 1) a1[t] = s1;
    if (natt > 2) a2[t] = s2;
}

// ---------- CSR aggregation: one wave per dst node ----------
__global__ __launch_bounds__(256)
void aggregate(const int* __restrict__ rowptr, const int* __restrict__ csr_src,
               const float* __restrict__ a_src, const float* __restrict__ a_dst,
               const unsigned short* __restrict__ h_src, unsigned short* __restrict__ outbf)
{
    int wid = (blockIdx.x * 256 + threadIdx.x) >> 6;
    int lane = threadIdx.x & 63;
    if (wid >= N_NODES) return;
    int beg = rowptr[wid], end = rowptr[wid + 1];
    int hh = lane & 7;
    float adst = a_dst[wid * H + hh];

    float amax = -1e30f;
    for (int p = beg; p < end; ++p) {
        int s = csr_src[p];
        float al = a_src[s * H + hh] + adst;
        al = (al >= 0.f) ? al : NEG_SLOPE * al;
        amax = fmaxf(amax, al);
    }
    float denom = 0.f;
    for (int p = beg; p < end; ++p) {
        int s = csr_src[p];
        float al = a_src[s * H + hh] + adst;
        al = (al >= 0.f) ? al : NEG_SLOPE * al;
        denom += expf(al - amax);
    }
    float inv = 1.f / (denom + 1e-16f);

    float acc[8] = {0.f, 0.f, 0.f, 0.f, 0.f, 0.f, 0.f, 0.f};
    for (int p = beg; p < end; ++p) {
        int s = csr_src[p];
        float al = a_src[s * H + hh] + adst;
        al = (al >= 0.f) ? al : NEG_SLOPE * al;
        float w = expf(al - amax) * inv;
        const unsigned short* hp = h_src + (size_t)s * D;
        #pragma unroll
        for (int h2 = 0; h2 < 8; ++h2) {
            float wh = __shfl(w, h2);   // lane h2 holds head h2's weight
            acc[h2] += bf2f(hp[h2 * 64 + lane]) * wh;
        }
    }
    size_t base = (size_t)wid * D;
    #pragma unroll
    for (int h2 = 0; h2 < 8; ++h2)
        outbf[base + h2 * 64 + lane] = f2bf(fmaxf(acc[h2], 0.f));
}

// ---------- column sums of relu'd bf16 matrix ----------
__global__ __launch_bounds__(256)
void colsum_bf16(const unsigned short* __restrict__ ob, float* __restrict__ colsum)
{
    __shared__ float red[512];
    int t = threadIdx.x;
    int r0 = blockIdx.x * 128;
    int c8 = t & 63;
    float s[8] = {0.f, 0.f, 0.f, 0.f, 0.f, 0.f, 0.f, 0.f};
    for (int it = 0; it < 32; ++it) {
        int row = r0 + it * 4 + (t >> 6);
        if (row < N_NODES) {
            uint4 v = *((const uint4*)(ob + (size_t)row * D) + c8);
            s[0] += bf2f((unsigned short)(v.x & 0xFFFF)); s[1] += bf2f((unsigned short)(v.x >> 16));
            s[2] += bf2f((unsigned short)(v.y & 0xFFFF)); s[3] += bf2f((unsigned short)(v.y >> 16));
            s[4] += bf2f((unsigned short)(v.z & 0xFFFF)); s[5] += bf2f((unsigned short)(v.z >> 16));
            s[6] += bf2f((unsigned short)(v.w & 0xFFFF)); s[7] += bf2f((unsigned short)(v.w >> 16));
        }
    }
    red[t] = 0.f; red[t + 256] = 0.f;
    __syncthreads();
    #pragma unroll
    for (int j = 0; j < 8; ++j) atomicAdd(&red[c8 * 8 + j], s[j]);
    __syncthreads();
    atomicAdd(&colsum[t], red[t]);
    atomicAdd(&colsum[t + 256], red[t + 256]);
}

// ---------- final semantic softmax + pool + linear ----------
__global__ __launch_bounds__(256)
void finalize(const float* __restrict__ ksum, const float* __restrict__ colsum,
              const float* __restrict__ q_sem, const float* __restrict__ lin_w,
              const float* __restrict__ lin_b, float* __restrict__ dout)
{
    __shared__ float red[256];
    __shared__ float semsh[2];
    int t = threadIdx.x;
    const float invN = 1.0f / (float)N_NODES;
    float p0 = ksum[t] * q_sem[t] + ksum[t + 256] * q_sem[t + 256];
    float p1 = ksum[512 + t] * q_sem[t] + ksum[512 + t + 256] * q_sem[t + 256];

    red[t] = p0; __syncthreads();
    for (int s = 128; s > 0; s >>= 1) { if (t < s) red[t] += red[t + s]; __syncthreads(); }
    float S0 = red[0]; __syncthreads();
    red[t] = p1; __syncthreads();
    for (int s = 128; s > 0; s >>= 1) { if (t < s) red[t] += red[t + s]; __syncthreads(); }
    float S1 = red[0]; __syncthreads();

    if (t == 0) {
        float a0 = S0 * invN, a1 = S1 * invN;
        float mx = fmaxf(a0, a1);
        float e0 = expf(a0 - mx), e1 = expf(a1 - mx);
        semsh[0] = e0 / (e0 + e1);
        semsh[1] = e1 / (e0 + e1);
    }
    __syncthreads();
    float sem0 = semsh[0], sem1 = semsh[1];

    float o0 = 0.f, o1 = 0.f;
    #pragma unroll
    for (int q = 0; q < 2; ++q) {
        int f = t + q * 256;
        float pooled = (sem0 * colsum[f] + sem1 * colsum[512 + f]) * invN;
        o0 += pooled * lin_w[f * 2 + 0];
        o1 += pooled * lin_w[f * 2 + 1];
    }
    red[t] = o0; __syncthreads();
    for (int s = 128; s > 0; s >>= 1) { if (t < s) red[t] += red[t + s]; __syncthreads(); }
    if (t == 0) dout[0] = red[0] + lin_b[0];
    __syncthreads();
    red[t] = o1; __syncthreads();
    for (int s = 128; s > 0; s >>= 1) { if (t < s) red[t] += red[t + s]; __syncthreads(); }
    if (t == 0) dout[1] = red[0] + lin_b[1];
}

extern "C" void kernel_launch(void* const* d_in, const int* in_sizes, int n_in,
                              void* d_out, int out_size, void* d_ws, size_t ws_size,
                              hipStream_t stream)
{
    const float* x_o    = (const float*)d_in[0];
    const float* x_e    = (const float*)d_in[1];
    const int*   e2o    = (const int*)d_in[2];
    const int*   o2o    = (const int*)d_in[3];
    const float* pow_   = (const float*)d_in[4];
    const float* pob    = (const float*)d_in[5];
    const float* pew    = (const float*)d_in[6];
    const float* peb    = (const float*)d_in[7];
    const float* as_e2o = (const float*)d_in[8];
    const float* ad_e2o = (const float*)d_in[9];
    const float* as_o2o = (const float*)d_in[10];
    const float* ad_o2o = (const float*)d_in[11];
    const float* klw    = (const float*)d_in[12];
    const float* klb    = (const float*)d_in[13];
    const float* qsem   = (const float*)d_in[14];
    const float* linw   = (const float*)d_in[15];
    const float* linb   = (const float*)d_in[16];

    char* ws = (char*)d_ws;
    size_t off = 0;
    auto alloc = [&](size_t bytes) { void* p = ws + off; off += (bytes + 255) & ~(size_t)255; return p; };

    unsigned short* h_o   = (unsigned short*)alloc((size_t)N_NODES * D * 2);
    unsigned short* h_e   = (unsigned short*)alloc((size_t)N_NODES * D * 2);
    unsigned short* outbf = (unsigned short*)alloc((size_t)N_NODES * D * 2);
    unsigned short* wt_po = (unsigned short*)alloc((size_t)D * D * 2);
    unsigned short* wt_pe = (unsigned short*)alloc((size_t)D * D * 2);
    unsigned short* wt_kl = (unsigned short*)alloc((size_t)D * D * 2);
    float* aS0 = (float*)alloc((size_t)N_NODES * H * 4);
    float* aD0 = (float*)alloc((size_t)N_NODES * H * 4);
    float* aS1 = (float*)alloc((size_t)N_NODES * H * 4);
    float* aD1 = (float*)alloc((size_t)N_NODES * H * 4);
    float* colsum = (float*)alloc(2048 * 4);         // colsum[1024] then ksum[1024], contiguous
    float* ksum   = colsum + 1024;
    int* deg     = (int*)alloc(2 * N_NODES * 4);
    int* cursor  = (int*)alloc(2 * N_NODES * 4);
    int* rowptr  = (int*)alloc((2 * N_NODES + 1) * 4);
    int* partials= (int*)alloc(256 * 4);
    int* csr     = (int*)alloc(2 * N_EDGES * 4);

    const int NSC = 2 * N_NODES;                      // scanned elements
    const int NB1 = (NSC + 1023) / 1024;              // 196 scan blocks
    const int EH  = (2 * N_EDGES + 255) / 256;        // 1172

    // zero colsum+ksum, zero deg
    zero_kernel<<<2, 256, 0, stream>>>((float4*)colsum, 512);
    zero_kernel<<<(NSC / 4 + 255) / 256, 256, 0, stream>>>((float4*)deg, NSC / 4);

    // CSR build (both metapaths in one combined structure)
    hist_edges<<<EH, 256, 0, stream>>>(e2o, o2o, deg);
    scan1<<<NB1, 256, 0, stream>>>(deg, rowptr, partials, NSC);
    scan2<<<1, 256, 0, stream>>>(partials, NB1);
    scan3<<<NB1, 256, 0, stream>>>(rowptr, partials, cursor, NSC, 2 * N_EDGES);
    fill_csr<<<EH, 256, 0, stream>>>(e2o, o2o, cursor, csr);

    // weights -> bf16 W^T
    dim3 tg(16, 16);
    transpose_to_bf16<<<tg, 256, 0, stream>>>(pow_, wt_po);
    transpose_to_bf16<<<tg, 256, 0, stream>>>(pew, wt_pe);
    transpose_to_bf16<<<tg, 256, 0, stream>>>(klw, wt_kl);

    // projections
    dim3 gg(D / 128, (N_NODES + 127) / 128);
    gemm_proj<<<gg, 256, 0, stream>>>(x_o, wt_po, pob, h_o, N_NODES);
    gemm_proj<<<gg, 256, 0, stream>>>(x_e, wt_pe, peb, h_e, N_NODES);

    // attention a-vectors
    const int nh_blocks = (N_NODES * H + 255) / 256;
    compute_a3<<<nh_blocks, 256, 0, stream>>>(h_o, ad_e2o, as_o2o, ad_o2o, aD0, aS1, aD1, 3);
    compute_a3<<<nh_blocks, 256, 0, stream>>>(h_e, as_e2o, as_e2o, as_e2o, aS0, aS0, aS0, 1);

    const int agg_blocks = (N_NODES * 64 + 255) / 256;
    const int cs_blocks = (N_NODES + 127) / 128;

    // metapath 0: e2o (src features h_e)
    aggregate<<<agg_blocks, 256, 0, stream>>>(rowptr, csr, aS0, aD0, h_e, outbf);
    colsum_bf16<<<cs_blocks, 256, 0, stream>>>(outbf, colsum);
    gemm_tanh<<<gg, 256, 0, stream>>>(outbf, wt_kl, klb, ksum, N_NODES);

    // metapath 1: o2o (src features h_o)
    aggregate<<<agg_blocks, 256, 0, stream>>>(rowptr + N_NODES, csr, aS1, aD1, h_o, outbf);
    colsum_bf16<<<cs_blocks, 256, 0, stream>>>(outbf, colsum + 512);
    gemm_tanh<<<gg, 256, 0, stream>>>(outbf, wt_kl, klb, ksum + 512, N_NODES);

    finalize<<<1, 256, 0, stream>>>(ksum, colsum, qsem, linw, linb, (float*)d_out);
}

// Round 4
// 1252.895 us; speedup vs baseline: 3.6685x; 1.0201x over previous
//
#include <hip/hip_runtime.h>
#include <math.h>

#define N_NODES 100000
#define N_EDGES 150000
#define D 512
#define H 8
#define NEG_SLOPE 0.2f
#define NBR 782          // row blocks of 128 over 100000 rows
#define NBLK (NBR * 4)   // 3128 blocks per GEMM half

typedef __attribute__((ext_vector_type(8))) short bf16x8;
typedef __attribute__((ext_vector_type(4))) float f32x4;

// ---------- helpers ----------
__device__ __forceinline__ float bf2f(unsigned short u) { return __uint_as_float(((unsigned int)u) << 16); }
__device__ __forceinline__ unsigned short f2bf(float f) {
    unsigned int u = __float_as_uint(f);
    unsigned int r = u + 0x7FFFu + ((u >> 16) & 1u);
    return (unsigned short)(r >> 16);
}
__device__ __forceinline__ unsigned int pkbf(float a, float b) {
    unsigned int ua = __float_as_uint(a) + 0x8000u;
    unsigned int ub = __float_as_uint(b) + 0x8000u;
    return (ua >> 16) | (ub & 0xFFFF0000u);
}
__device__ __forceinline__ void gl_lds16(const void* g, void* l) {
    __builtin_amdgcn_global_load_lds((const __attribute__((address_space(1))) void*)g,
                                     (__attribute__((address_space(3))) void*)l, 16, 0, 0);
}
// XCD-aware swizzle: groups of 32 linear ids = 8 row-blocks x 4 col-blocks;
// id%8 (the XCD on round-robin dispatch) is the row-block within the group, so
// the 4 col tiles of one row-block share an XCD -> A rows fetched once from HBM.
__device__ __forceinline__ void map_block(int lin, int& rblk, int& cblk) {
    int g = lin >> 5;
    if (g < (NBR >> 3)) { rblk = g * 8 + (lin & 7); cblk = (lin >> 3) & 3; }
    else { int idx = lin - (NBR >> 3) * 32; rblk = (NBR & ~7) + (idx >> 2); cblk = idx & 3; }
}

// ---------- CSR build ----------
__global__ __launch_bounds__(256)
void hist_edges(const int* __restrict__ e2o, const int* __restrict__ o2o, int* __restrict__ deg) {
    int i = blockIdx.x * 256 + threadIdx.x;
    if (i < N_EDGES) atomicAdd(&deg[e2o[N_EDGES + i]], 1);
    else if (i < 2 * N_EDGES) atomicAdd(&deg[N_NODES + o2o[N_EDGES + (i - N_EDGES)]], 1);
}

__global__ __launch_bounds__(256)
void scan1(const int* __restrict__ deg, int* __restrict__ rowptr, int* __restrict__ partials, int n) {
    __shared__ int lds[256];
    int t = threadIdx.x, b = blockIdx.x;
    int base = b * 1024 + t * 4;
    int d0 = (base + 0 < n) ? deg[base + 0] : 0;
    int d1 = (base + 1 < n) ? deg[base + 1] : 0;
    int d2 = (base + 2 < n) ? deg[base + 2] : 0;
    int d3 = (base + 3 < n) ? deg[base + 3] : 0;
    int s = d0 + d1 + d2 + d3;
    lds[t] = s;
    __syncthreads();
    for (int off = 1; off < 256; off <<= 1) {
        int v = (t >= off) ? lds[t - off] : 0;
        __syncthreads();
        lds[t] += v;
        __syncthreads();
    }
    int incl = lds[t];
    int eb = incl - s;
    if (base + 0 < n) rowptr[base + 0] = eb;
    if (base + 1 < n) rowptr[base + 1] = eb + d0;
    if (base + 2 < n) rowptr[base + 2] = eb + d0 + d1;
    if (base + 3 < n) rowptr[base + 3] = eb + d0 + d1 + d2;
    if (t == 255) partials[b] = incl;
}

// merged scan2+scan3: every block redundantly scans the (<=256) partials in LDS
__global__ __launch_bounds__(256)
void scan23(int* __restrict__ rowptr, const int* __restrict__ partials,
            int* __restrict__ cursor, int n, int total, int nb) {
    __shared__ int lds[256];
    int t = threadIdx.x, b = blockIdx.x;
    lds[t] = (t < nb) ? partials[t] : 0;
    __syncthreads();
    for (int off = 1; off < 256; off <<= 1) {
        int v = (t >= off) ? lds[t - off] : 0;
        __syncthreads();
        lds[t] += v;
        __syncthreads();
    }
    int add = (b == 0) ? 0 : lds[b - 1];
    int base = b * 1024 + t * 4;
    #pragma unroll
    for (int j = 0; j < 4; ++j) {
        if (base + j < n) {
            int v = rowptr[base + j] + add;
            rowptr[base + j] = v;
            cursor[base + j] = v;
        }
    }
    if (b == 0 && t == 0) rowptr[n] = total;
}

__global__ __launch_bounds__(256)
void fill_csr(const int* __restrict__ e2o, const int* __restrict__ o2o,
              int* __restrict__ cursor, int* __restrict__ csr) {
    int i = blockIdx.x * 256 + threadIdx.x;
    if (i < N_EDGES) {
        int d = e2o[N_EDGES + i];
        int p = atomicAdd(&cursor[d], 1);
        csr[p] = e2o[i];
    } else if (i < 2 * N_EDGES) {
        int j = i - N_EDGES;
        int d = o2o[N_EDGES + j];
        int p = atomicAdd(&cursor[N_NODES + d], 1);
        csr[p] = o2o[j];
    }
}

// ---------- three W[512,512] fp32 -> Wt[n][k] bf16 in one dispatch ----------
__global__ __launch_bounds__(256)
void transpose3(const float* __restrict__ W0, const float* __restrict__ W1, const float* __restrict__ W2,
                unsigned short* __restrict__ T0, unsigned short* __restrict__ T1, unsigned short* __restrict__ T2) {
    __shared__ float tile[32][33];
    int z = blockIdx.z;
    const float* W = (z == 0) ? W0 : (z == 1) ? W1 : W2;
    unsigned short* T = (z == 0) ? T0 : (z == 1) ? T1 : T2;
    int bx = blockIdx.x, by = blockIdx.y;
    int t = threadIdx.x, tx = t & 31, ty = t >> 5;
    #pragma unroll
    for (int p = 0; p < 4; ++p) {
        int k = by * 32 + ty + p * 8;
        tile[ty + p * 8][tx] = W[(size_t)k * D + bx * 32 + tx];
    }
    __syncthreads();
    #pragma unroll
    for (int p = 0; p < 4; ++p) {
        int n = bx * 32 + ty + p * 8;
        T[(size_t)n * D + by * 32 + tx] = f2bf(tile[tx][ty + p * 8]);
    }
}

// ---------- x_o, x_e fp32 -> bf16 in one dispatch ----------
__global__ __launch_bounds__(256)
void convert2(const float4* __restrict__ x0, const float4* __restrict__ x1,
              uint2* __restrict__ y0, uint2* __restrict__ y1) {
    const int n4 = N_NODES * D / 4;
    int i = blockIdx.x * 256 + threadIdx.x;
    const float4* s; uint2* d; int j;
    if (i < n4) { s = x0; d = y0; j = i; }
    else { s = x1; d = y1; j = i - n4; }
    float4 v = s[j];
    uint2 o; o.x = pkbf(v.x, v.y); o.y = pkbf(v.z, v.w);
    d[j] = o;
}

// ---------- merged projection GEMMs + fused per-head attention dots ----------
// half 0: C0 = A0 @ Bt0^T + b0 (x_o proj), emits 3 a-vectors (aD0,aS1,aD1)
// half 1: C1 = A1 @ Bt1^T + b1 (x_e proj), emits 1 a-vector (aS0)
__global__ __launch_bounds__(256)
void gemm_proj2(const unsigned short* __restrict__ A0, const unsigned short* __restrict__ A1,
                const unsigned short* __restrict__ Bt0, const unsigned short* __restrict__ Bt1,
                const float* __restrict__ b0, const float* __restrict__ b1,
                unsigned short* __restrict__ C0, unsigned short* __restrict__ C1,
                const float* __restrict__ at00, const float* __restrict__ at01, const float* __restrict__ at02,
                float* __restrict__ ao00, float* __restrict__ ao01, float* __restrict__ ao02,
                const float* __restrict__ at10, float* __restrict__ ao10)
{
    __shared__ __align__(16) unsigned short As[4096];   // 8 subtiles of [16 rows][32 k], fragment order
    __shared__ __align__(16) unsigned short Bs[4096];
    const int M = N_NODES;
    int lin = blockIdx.x;
    int half = (lin >= NBLK) ? 1 : 0;
    lin -= half * NBLK;
    int rblk, cblk; map_block(lin, rblk, cblk);
    const unsigned short* A  = half ? A1 : A0;
    const unsigned short* Bt = half ? Bt1 : Bt0;
    const float* bias        = half ? b1 : b0;
    unsigned short* C        = half ? C1 : C0;
    const int natt = half ? 1 : 3;
    const float* attA = half ? at10 : at00;
    const float* attB = at01;
    const float* attC = at02;
    float* aoA = half ? ao10 : ao00;
    float* aoB = ao01;
    float* aoC = ao02;

    const int tid = threadIdx.x, lane = tid & 63, wave = tid >> 6;
    const int rb = rblk * 128, cb = cblk * 128;
    const int wm = (wave >> 1) * 64, wn = (wave & 1) * 64;

    // staging: each wave fills subtiles {2w, 2w+1} of A and B.
    // lane l -> row (l&15) of subtile, k-chunk (l>>4)*8 elems; LDS dest = base + l*16B
    const unsigned short* agp[2]; const unsigned short* bgp[2];
    unsigned short *ald[2], *bld[2];
    #pragma unroll
    for (int c = 0; c < 2; ++c) {
        int s = wave * 2 + c;
        int rA = rb + s * 16 + (lane & 15); if (rA > M - 1) rA = M - 1;
        agp[c] = A + (size_t)rA * D + (lane >> 4) * 8;
        ald[c] = &As[s * 512];
        int rB = cb + s * 16 + (lane & 15);
        bgp[c] = Bt + (size_t)rB * D + (lane >> 4) * 8;
        bld[c] = &Bs[s * 512];
    }

    f32x4 acc[4][4];
    #pragma unroll
    for (int i = 0; i < 4; ++i)
        #pragma unroll
        for (int j = 0; j < 4; ++j) acc[i][j] = (f32x4){0.f, 0.f, 0.f, 0.f};

    for (int k = 0; k < 16; ++k) {
        if (k) __syncthreads();
        #pragma unroll
        for (int c = 0; c < 2; ++c) {
            gl_lds16(agp[c], ald[c]); agp[c] += 32;
            gl_lds16(bgp[c], bld[c]); bgp[c] += 32;
        }
        __syncthreads();
        bf16x8 af[4], bfr[4];
        #pragma unroll
        for (int mi = 0; mi < 4; ++mi) af[mi] = *(const bf16x8*)&As[((wave >> 1) * 4 + mi) * 512 + lane * 8];
        #pragma unroll
        for (int ni = 0; ni < 4; ++ni) bfr[ni] = *(const bf16x8*)&Bs[((wave & 1) * 4 + ni) * 512 + lane * 8];
        #pragma unroll
        for (int mi = 0; mi < 4; ++mi)
            #pragma unroll
            for (int ni = 0; ni < 4; ++ni)
                acc[mi][ni] = __builtin_amdgcn_mfma_f32_16x16x32_bf16(af[mi], bfr[ni], acc[mi][ni], 0, 0, 0);
    }

    // epilogue: bias + bf16 store + per-head attention dots (this wave's 64 cols = one head)
    float bb[4], av0[4], av1[4], av2[4];
    const int head = (cb + wn) >> 6;
    #pragma unroll
    for (int ni = 0; ni < 4; ++ni) {
        int ci = ni * 16 + (lane & 15);
        bb[ni] = bias[cb + wn + ci];
        av0[ni] = attA[head * 64 + ci];
        if (natt > 1) { av1[ni] = attB[head * 64 + ci]; av2[ni] = attC[head * 64 + ci]; }
    }
    #pragma unroll
    for (int mi = 0; mi < 4; ++mi) {
        #pragma unroll
        for (int r = 0; r < 4; ++r) {
            int rg = rb + wm + mi * 16 + (lane >> 4) * 4 + r;
            bool ok = rg < M;
            float v[4];
            #pragma unroll
            for (int ni = 0; ni < 4; ++ni) v[ni] = acc[mi][ni][r] + bb[ni];
            if (ok) {
                size_t base = (size_t)rg * D + cb + wn + (lane & 15);
                #pragma unroll
                for (int ni = 0; ni < 4; ++ni) C[base + ni * 16] = f2bf(v[ni]);
            }
            float s0 = v[0] * av0[0] + v[1] * av0[1] + v[2] * av0[2] + v[3] * av0[3];
            float s1 = 0.f, s2 = 0.f;
            if (natt > 1) {
                s1 = v[0] * av1[0] + v[1] * av1[1] + v[2] * av1[2] + v[3] * av1[3];
                s2 = v[0] * av2[0] + v[1] * av2[1] + v[2] * av2[2] + v[3] * av2[3];
            }
            #pragma unroll
            for (int m2 = 1; m2 < 16; m2 <<= 1) {
                s0 += __shfl_xor(s0, m2);
                if (natt > 1) { s1 += __shfl_xor(s1, m2); s2 += __shfl_xor(s2, m2); }
            }
            if (ok && (lane & 15) == 0) {
                aoA[rg * H + head] = s0;
                if (natt > 1) { aoB[rg * H + head] = s1; aoC[rg * H + head] = s2; }
            }
        }
    }
}

// ---------- merged CSR aggregation (both metapaths): one wave per dst node ----------
__global__ __launch_bounds__(256)
void aggregate2(const int* __restrict__ rowptr, const int* __restrict__ csr,
                const float* __restrict__ aS0, const float* __restrict__ aD0, const unsigned short* __restrict__ hE,
                const float* __restrict__ aS1, const float* __restrict__ aD1, const unsigned short* __restrict__ hO,
                unsigned short* __restrict__ out0, unsigned short* __restrict__ out1)
{
    int gw = (blockIdx.x * 256 + threadIdx.x) >> 6;
    int lane = threadIdx.x & 63;
    if (gw >= 2 * N_NODES) return;
    int half = gw >= N_NODES;
    int node = gw - half * N_NODES;
    const float* a_src = half ? aS1 : aS0;
    const float* a_dst = half ? aD1 : aD0;
    const unsigned short* h = half ? hO : hE;
    unsigned short* out = half ? out1 : out0;

    int beg = rowptr[gw], end = rowptr[gw + 1];
    int hh = lane & 7;
    float adst = a_dst[node * H + hh];

    float amax = -1e30f;
    for (int p = beg; p < end; ++p) {
        int s = csr[p];
        float al = a_src[s * H + hh] + adst;
        al = (al >= 0.f) ? al : NEG_SLOPE * al;
        amax = fmaxf(amax, al);
    }
    float denom = 0.f;
    for (int p = beg; p < end; ++p) {
        int s = csr[p];
        float al = a_src[s * H + hh] + adst;
        al = (al >= 0.f) ? al : NEG_SLOPE * al;
        denom += expf(al - amax);
    }
    float inv = 1.f / (denom + 1e-16f);

    float acc[8] = {0.f, 0.f, 0.f, 0.f, 0.f, 0.f, 0.f, 0.f};
    for (int p = beg; p < end; ++p) {
        int s = csr[p];
        float al = a_src[s * H + hh] + adst;
        al = (al >= 0.f) ? al : NEG_SLOPE * al;
        float w = expf(al - amax) * inv;
        const unsigned short* hp = h + (size_t)s * D;
        #pragma unroll
        for (int h2 = 0; h2 < 8; ++h2) {
            float wh = __shfl(w, h2);
            acc[h2] += bf2f(hp[h2 * 64 + lane]) * wh;
        }
    }
    size_t base = (size_t)node * D;
    #pragma unroll
    for (int h2 = 0; h2 < 8; ++h2)
        out[base + h2 * 64 + lane] = f2bf(fmaxf(acc[h2], 0.f));
}

// ---------- merged column sums of both relu'd bf16 matrices ----------
__global__ __launch_bounds__(256)
void colsum2(const unsigned short* __restrict__ ob0, const unsigned short* __restrict__ ob1,
             float* __restrict__ colsum)
{
    __shared__ float red[512];
    int b = blockIdx.x;
    int half = b >= NBR;
    const unsigned short* ob = half ? ob1 : ob0;
    float* cs = colsum + half * 512;
    int t = threadIdx.x;
    int r0 = (b - half * NBR) * 128;
    int c8 = t & 63;
    float s[8] = {0.f, 0.f, 0.f, 0.f, 0.f, 0.f, 0.f, 0.f};
    for (int it = 0; it < 32; ++it) {
        int row = r0 + it * 4 + (t >> 6);
        if (row < N_NODES) {
            uint4 v = *((const uint4*)(ob + (size_t)row * D) + c8);
            s[0] += bf2f((unsigned short)(v.x & 0xFFFF)); s[1] += bf2f((unsigned short)(v.x >> 16));
            s[2] += bf2f((unsigned short)(v.y & 0xFFFF)); s[3] += bf2f((unsigned short)(v.y >> 16));
            s[4] += bf2f((unsigned short)(v.z & 0xFFFF)); s[5] += bf2f((unsigned short)(v.z >> 16));
            s[6] += bf2f((unsigned short)(v.w & 0xFFFF)); s[7] += bf2f((unsigned short)(v.w >> 16));
        }
    }
    red[t] = 0.f; red[t + 256] = 0.f;
    __syncthreads();
    #pragma unroll
    for (int j = 0; j < 8; ++j) atomicAdd(&red[c8 * 8 + j], s[j]);
    __syncthreads();
    atomicAdd(&cs[t & 511], red[t]);
    atomicAdd(&cs[(t + 256) & 511], red[t + 256]);
}

// ---------- merged semantic-K GEMMs: ksum[half][f] += sum_rows tanh((A@Wkl^T + b)[row,f]) ----------
__global__ __launch_bounds__(256)
void gemm_tanh2(const unsigned short* __restrict__ Ah0, const unsigned short* __restrict__ Ah1,
                const unsigned short* __restrict__ Bt, const float* __restrict__ bias,
                float* __restrict__ ksum)
{
    __shared__ __align__(16) unsigned short As[4096];
    __shared__ __align__(16) unsigned short Bs[4096];
    const int M = N_NODES;
    int lin = blockIdx.x;
    int half = (lin >= NBLK) ? 1 : 0;
    lin -= half * NBLK;
    int rblk, cblk; map_block(lin, rblk, cblk);
    const unsigned short* A = half ? Ah1 : Ah0;
    float* ks = ksum + half * 512;

    const int tid = threadIdx.x, lane = tid & 63, wave = tid >> 6;
    const int rb = rblk * 128, cb = cblk * 128;
    const int wm = (wave >> 1) * 64, wn = (wave & 1) * 64;

    const unsigned short* agp[2]; const unsigned short* bgp[2];
    unsigned short *ald[2], *bld[2];
    #pragma unroll
    for (int c = 0; c < 2; ++c) {
        int s = wave * 2 + c;
        int rA = rb + s * 16 + (lane & 15); if (rA > M - 1) rA = M - 1;
        agp[c] = A + (size_t)rA * D + (lane >> 4) * 8;
        ald[c] = &As[s * 512];
        int rB = cb + s * 16 + (lane & 15);
        bgp[c] = Bt + (size_t)rB * D + (lane >> 4) * 8;
        bld[c] = &Bs[s * 512];
    }

    f32x4 acc[4][4];
    #pragma unroll
    for (int i = 0; i < 4; ++i)
        #pragma unroll
        for (int j = 0; j < 4; ++j) acc[i][j] = (f32x4){0.f, 0.f, 0.f, 0.f};

    for (int k = 0; k < 16; ++k) {
        if (k) __syncthreads();
        #pragma unroll
        for (int c = 0; c < 2; ++c) {
            gl_lds16(agp[c], ald[c]); agp[c] += 32;
            gl_lds16(bgp[c], bld[c]); bgp[c] += 32;
        }
        __syncthreads();
        bf16x8 af[4], bfr[4];
        #pragma unroll
        for (int mi = 0; mi < 4; ++mi) af[mi] = *(const bf16x8*)&As[((wave >> 1) * 4 + mi) * 512 + lane * 8];
        #pragma unroll
        for (int ni = 0; ni < 4; ++ni) bfr[ni] = *(const bf16x8*)&Bs[((wave & 1) * 4 + ni) * 512 + lane * 8];
        #pragma unroll
        for (int mi = 0; mi < 4; ++mi)
            #pragma unroll
            for (int ni = 0; ni < 4; ++ni)
                acc[mi][ni] = __builtin_amdgcn_mfma_f32_16x16x32_bf16(af[mi], bfr[ni], acc[mi][ni], 0, 0, 0);
    }

    float bb[4];
    #pragma unroll
    for (int ni = 0; ni < 4; ++ni) bb[ni] = bias[cb + wn + ni * 16 + (lane & 15)];
    float cs[4] = {0.f, 0.f, 0.f, 0.f};
    #pragma unroll
    for (int mi = 0; mi < 4; ++mi) {
        #pragma unroll
        for (int r = 0; r < 4; ++r) {
            int rg = rb + wm + mi * 16 + (lane >> 4) * 4 + r;
            if (rg < M) {
                #pragma unroll
                for (int ni = 0; ni < 4; ++ni)
                    cs[ni] += tanhf(acc[mi][ni][r] + bb[ni]);
            }
        }
    }
    __syncthreads();
    float* red = (float*)As;
    if (tid < 128) red[tid] = 0.f;
    __syncthreads();
    #pragma unroll
    for (int ni = 0; ni < 4; ++ni) atomicAdd(&red[wn + ni * 16 + (lane & 15)], cs[ni]);
    __syncthreads();
    if (tid < 128) atomicAdd(&ks[cb + tid], red[tid]);
}

// ---------- final semantic softmax + pool + linear ----------
__global__ __launch_bounds__(256)
void finalize(const float* __restrict__ ksum, const float* __restrict__ colsum,
              const float* __restrict__ q_sem, const float* __restrict__ lin_w,
              const float* __restrict__ lin_b, float* __restrict__ dout)
{
    __shared__ float red[256];
    __shared__ float semsh[2];
    int t = threadIdx.x;
    const float invN = 1.0f / (float)N_NODES;
    float p0 = ksum[t] * q_sem[t] + ksum[t + 256] * q_sem[t + 256];
    float p1 = ksum[512 + t] * q_sem[t] + ksum[512 + t + 256] * q_sem[t + 256];

    red[t] = p0; __syncthreads();
    for (int s = 128; s > 0; s >>= 1) { if (t < s) red[t] += red[t + s]; __syncthreads(); }
    float S0 = red[0]; __syncthreads();
    red[t] = p1; __syncthreads();
    for (int s = 128; s > 0; s >>= 1) { if (t < s) red[t] += red[t + s]; __syncthreads(); }
    float S1 = red[0]; __syncthreads();

    if (t == 0) {
        float a0 = S0 * invN, a1 = S1 * invN;
        float mx = fmaxf(a0, a1);
        float e0 = expf(a0 - mx), e1 = expf(a1 - mx);
        semsh[0] = e0 / (e0 + e1);
        semsh[1] = e1 / (e0 + e1);
    }
    __syncthreads();
    float sem0 = semsh[0], sem1 = semsh[1];

    float o0 = 0.f, o1 = 0.f;
    #pragma unroll
    for (int q = 0; q < 2; ++q) {
        int f = t + q * 256;
        float pooled = (sem0 * colsum[f] + sem1 * colsum[512 + f]) * invN;
        o0 += pooled * lin_w[f * 2 + 0];
        o1 += pooled * lin_w[f * 2 + 1];
    }
    red[t] = o0; __syncthreads();
    for (int s = 128; s > 0; s >>= 1) { if (t < s) red[t] += red[t + s]; __syncthreads(); }
    if (t == 0) dout[0] = red[0] + lin_b[0];
    __syncthreads();
    red[t] = o1; __syncthreads();
    for (int s = 128; s > 0; s >>= 1) { if (t < s) red[t] += red[t + s]; __syncthreads(); }
    if (t == 0) dout[1] = red[0] + lin_b[1];
}

extern "C" void kernel_launch(void* const* d_in, const int* in_sizes, int n_in,
                              void* d_out, int out_size, void* d_ws, size_t ws_size,
                              hipStream_t stream)
{
    const float* x_o    = (const float*)d_in[0];
    const float* x_e    = (const float*)d_in[1];
    const int*   e2o    = (const int*)d_in[2];
    const int*   o2o    = (const int*)d_in[3];
    const float* pow_   = (const float*)d_in[4];
    const float* pob    = (const float*)d_in[5];
    const float* pew    = (const float*)d_in[6];
    const float* peb    = (const float*)d_in[7];
    const float* as_e2o = (const float*)d_in[8];
    const float* ad_e2o = (const float*)d_in[9];
    const float* as_o2o = (const float*)d_in[10];
    const float* ad_o2o = (const float*)d_in[11];
    const float* klw    = (const float*)d_in[12];
    const float* klb    = (const float*)d_in[13];
    const float* qsem   = (const float*)d_in[14];
    const float* linw   = (const float*)d_in[15];
    const float* linb   = (const float*)d_in[16];

    char* ws = (char*)d_ws;
    size_t off = 0;
    auto alloc = [&](size_t bytes) { void* p = ws + off; off += (bytes + 255) & ~(size_t)255; return p; };

    unsigned short* xbf_o = (unsigned short*)alloc((size_t)N_NODES * D * 2);
    unsigned short* xbf_e = (unsigned short*)alloc((size_t)N_NODES * D * 2);
    unsigned short* h_o   = (unsigned short*)alloc((size_t)N_NODES * D * 2);
    unsigned short* h_e   = (unsigned short*)alloc((size_t)N_NODES * D * 2);
    unsigned short* obf0  = (unsigned short*)alloc((size_t)N_NODES * D * 2);
    unsigned short* obf1  = (unsigned short*)alloc((size_t)N_NODES * D * 2);
    unsigned short* wt_po = (unsigned short*)alloc((size_t)D * D * 2);
    unsigned short* wt_pe = (unsigned short*)alloc((size_t)D * D * 2);
    unsigned short* wt_kl = (unsigned short*)alloc((size_t)D * D * 2);
    float* aS0 = (float*)alloc((size_t)N_NODES * H * 4);
    float* aD0 = (float*)alloc((size_t)N_NODES * H * 4);
    float* aS1 = (float*)alloc((size_t)N_NODES * H * 4);
    float* aD1 = (float*)alloc((size_t)N_NODES * H * 4);
    // contiguous zeroed region: colsum[1024] | ksum[1024] | deg[2N]
    int* misc    = (int*)alloc((2048 + 2 * N_NODES) * 4);
    float* colsum = (float*)misc;
    float* ksum   = colsum + 1024;
    int* deg      = misc + 2048;
    int* cursor  = (int*)alloc(2 * N_NODES * 4);
    int* rowptr  = (int*)alloc((2 * N_NODES + 1) * 4);
    int* partials= (int*)alloc(256 * 4);
    int* csr     = (int*)alloc(2 * N_EDGES * 4);

    const int NSC = 2 * N_NODES;
    const int NB1 = (NSC + 1023) / 1024;              // 196
    const int EH  = (2 * N_EDGES + 255) / 256;        // 1172

    hipMemsetAsync(misc, 0, (size_t)(2048 + 2 * N_NODES) * 4, stream);

    // CSR build
    hist_edges<<<EH, 256, 0, stream>>>(e2o, o2o, deg);
    scan1<<<NB1, 256, 0, stream>>>(deg, rowptr, partials, NSC);
    scan23<<<NB1, 256, 0, stream>>>(rowptr, partials, cursor, NSC, 2 * N_EDGES, NB1);
    fill_csr<<<EH, 256, 0, stream>>>(e2o, o2o, cursor, csr);

    // weights -> bf16 W^T (one dispatch), inputs -> bf16 (one dispatch)
    transpose3<<<dim3(16, 16, 3), 256, 0, stream>>>(pow_, pew, klw, wt_po, wt_pe, wt_kl);
    convert2<<<(2 * N_NODES * D / 4) / 256, 256, 0, stream>>>(
        (const float4*)x_o, (const float4*)x_e, (uint2*)xbf_o, (uint2*)xbf_e);

    // merged projections + fused attention dots
    gemm_proj2<<<2 * NBLK, 256, 0, stream>>>(
        xbf_o, xbf_e, wt_po, wt_pe, pob, peb, h_o, h_e,
        ad_e2o, as_o2o, ad_o2o, aD0, aS1, aD1,
        as_e2o, aS0);

    // merged aggregation, column sums, semantic-K GEMMs
    aggregate2<<<(2 * N_NODES * 64) / 256, 256, 0, stream>>>(
        rowptr, csr, aS0, aD0, h_e, aS1, aD1, h_o, obf0, obf1);
    colsum2<<<2 * NBR, 256, 0, stream>>>(obf0, obf1, colsum);
    gemm_tanh2<<<2 * NBLK, 256, 0, stream>>>(obf0, obf1, wt_kl, klb, ksum);

    finalize<<<1, 256, 0, stream>>>(ksum, colsum, qsem, linw, linb, (float*)d_out);
}